// Round 3
// baseline (282.317 us; speedup 1.0000x reference)
//
#include <hip/hip_runtime.h>

// Frobenius — R12: R11 dataflow, barrier diet 5 -> 3 + shuffle-fold gathers.
//
// R11 post-mortem: 166.6 us, HBM 13%, VALUBusy 29.5%, 0 LDS conflicts ->
// still latency-bound at ~7.3 us/iter, of which ~5 us is sync machinery:
// 5 full-block barriers + vmcnt drain + flag RTT + gather RTT.
//
// R12 deletes 2 barriers and shortens the pre-flag chain:
//  - Row fold is WAVE-LOCAL (wave g only touches part[g]) -> publish rowF +
//    per-wave vmcnt(0) BEFORE A1. A2 deleted: after A1 all rowF stores are
//    already drained, so wave 0 folds cq, publishes colF, drains its own 2
//    stores, sets flag immediately.
//  - B-phase folds in-register: lane l of wave g gathers peer (l>>2), quad
//    (l&3) for BOTH its wave's 16 rows (rowF) and its wave's 16 cols (colF),
//    butterfly over lane bits 2..5. Row sums land in the owning wave (no
//    redistribution); col sums + sG broadcast via ONE barrier (B1). B2 gone.
//  - Pollers = waves 4..7 (t-256), so polling overlaps wave 0's fold+publish.
//
// Barriers/iter: A1 (cq ready), B0 (all flags observed; also WAR-protects cq
// vs next iter's writes), B1 (colq/sG broadcast; also WAR-protects them).
// WAR on colF/rowF/pflag: unchanged R11 transitive argument (any block
// entering iter k observed ALL flags at k-1, each set after that block
// finished its k-2 reads; parity double-buffer).
//
// Sync primitives (R5-R11 proven): all cross-block data via b64 relaxed
// agent atomics; data stores -> per-wave s_waitcnt vmcnt(0) -> (barrier) ->
// flag (tag<<32 | blocksum bits); exact-tag polls -> data arrays need no
// init; memset only pflag (32 KB).

#define NN    4096
#define NV4   1024
#define NBLK  256
#define ITERS 20
#define INV_N (1.0f / 4096.0f)

typedef unsigned long long u64;
typedef float f32x4 __attribute__((ext_vector_type(4)));

__device__ __forceinline__ float wave_reduce_sum(float v) {
    #pragma unroll
    for (int m = 1; m < 64; m <<= 1) v += __shfl_xor(v, m, 64);
    return v;
}
__device__ __forceinline__ void st_b64(u64* p, u64 v) {
    __hip_atomic_store(p, v, __ATOMIC_RELAXED, __HIP_MEMORY_SCOPE_AGENT);
}
__device__ __forceinline__ u64 ld_b64(const u64* p) {
    return __hip_atomic_load(p, __ATOMIC_RELAXED, __HIP_MEMORY_SCOPE_AGENT);
}
__device__ __forceinline__ u64 packf2(float a, float b) {
    return (u64)__float_as_uint(a) | ((u64)__float_as_uint(b) << 32);
}
__device__ __forceinline__ float lo32(u64 u) { return __uint_as_float((unsigned)u); }
__device__ __forceinline__ float hi32(u64 u) { return __uint_as_float((unsigned)(u >> 32)); }

__global__ __launch_bounds__(1024, 4)
void persist11(const float* __restrict__ X0, float* __restrict__ Xout,
               u64* __restrict__ colF,    // [2][256][128] b64 = 2 packed f32
               u64* __restrict__ rowF,    // [2][256][128]
               u64* __restrict__ pflag)   // [2][256] stride-8 u64 (64 B apart)
{
    const int t    = threadIdx.x;
    const int lane = t & 63;
    const int g    = t >> 6;          // wave = 16-row group
    const int c    = lane;            // 4-col quad
    const int b    = blockIdx.x;
    const int bi   = b >> 4;
    const int bj   = b & 15;

    // ~93.3 KB total -> 1 block/CU (grid == 256 == #CUs).
    __shared__ float part[16][64][21];   // row-partial transpose (86 KB),
                                         // stride 21: coprime-32 -> 2-way max
    __shared__ f32x4 cq[16][64];         // per-wave col partials (4 KB)
    __shared__ f32x4 colqAll[64];        // folded colsum quads (1 KB)
    __shared__ f32x4 rwave4[16][4];      // per-wave folded rowsum quads (1 KB)
    __shared__ float bsv[256];           // peer blocksums (1 KB)
    __shared__ float sG_s;               // grand total

    f32x4 x[16];
    {
        const f32x4* xi = (const f32x4*)X0;
        const size_t base = (size_t)(bi * 256 + g * 16) * NV4 + (bj * 64 + c);
        #pragma unroll
        for (int r = 0; r < 16; ++r)
            x[r] = xi[base + (size_t)r * NV4];
    }

    for (int iter = 0; iter < ITERS; ++iter) {
        const int p = iter & 1;
        const u64 tagv = (u64)(iter + 1);

        // ---- phase A: wave-local work first, publish rowF early
        f32x4 cacc = x[0];
        #pragma unroll
        for (int r = 1; r < 16; ++r) cacc += x[r];
        cq[g][c] = cacc;                              // per-wave col partial
        #pragma unroll
        for (int r = 0; r < 16; ++r)
            part[g][c][r] = (x[r].x + x[r].y) + (x[r].z + x[r].w);
        // wave-local LDS: writes above, reads below, same wave -> waitcnt only
        asm volatile("s_waitcnt lgkmcnt(0)" ::: "memory");
        {   // row fold: wave g's 16 rows over 64 col-quads (LDS transpose)
            const int r_ = lane & 15, q_ = lane >> 4;
            float v = 0.f;
            #pragma unroll
            for (int k = 0; k < 16; ++k) v += part[g][q_ * 16 + k][r_];
            v += __shfl_xor(v, 16, 64);
            v += __shfl_xor(v, 32, 64);
            float vp = __shfl_xor(v, 1, 64);          // partner row value
            if (lane < 16 && (lane & 1) == 0)         // 8 b64 per wave
                st_b64(rowF + (((size_t)(p * NBLK + b)) << 7) + 8 * g + (lane >> 1),
                       packf2(v, vp));
        }
        asm volatile("s_waitcnt vmcnt(0)" ::: "memory");  // own rowF drained
        __syncthreads();                                  // A1: cq ready,
                                                          // ALL rowF drained
        if (g == 0) {   // fold 16 waves' col partials, publish, flag
            f32x4 vq = cq[0][c];
            #pragma unroll
            for (int k = 1; k < 16; ++k) vq += cq[k][c];
            u64* dst = colF + (((size_t)(p * NBLK + b)) << 7) + 2 * c;
            st_b64(dst,     packf2(vq.x, vq.y));
            st_b64(dst + 1, packf2(vq.z, vq.w));
            float bs = wave_reduce_sum((vq.x + vq.y) + (vq.z + vq.w));
            asm volatile("s_waitcnt vmcnt(0)" ::: "memory");  // colF drained
            if (lane == 0)
                st_b64(pflag + ((size_t)(p * NBLK + b) << 3),
                       (tagv << 32) | (u64)__float_as_uint(bs));
        }
        // ---- rendezvous: waves 4..7 poll (overlaps wave 0's fold+publish)
        if (g >= 4 && g < 8) {
            const int f = t - 256;                    // one poller per flag
            const u64* fp = pflag + ((size_t)(p * NBLK + f) << 3);
            u64 u;
            while (((u = ld_b64(fp)) >> 32) != tagv)
                __builtin_amdgcn_s_sleep(1);
            bsv[f] = lo32(u);
        }
        asm volatile("" ::: "memory");
        __syncthreads();                              // B0: all flags seen;
                                                      // also cq-WAR fence

        // ---- phase B: gather + in-register butterfly folds
        {
            const int srcq = lane >> 2, q = lane & 3; // peer idx, quad idx
            const u64* cp = colF + (((size_t)(p * NBLK + srcq * 16 + bj)) << 7)
                                 + 8 * g + 2 * q;     // cols 16g+4q..+3
            const u64* rp = rowF + (((size_t)(p * NBLK + bi * 16 + srcq)) << 7)
                                 + 8 * g + 2 * q;     // rows 16g+4q..+3
            u64 c0 = ld_b64(cp), c1 = ld_b64(cp + 1);
            u64 r0 = ld_b64(rp), r1 = ld_b64(rp + 1);
            f32x4 cv, rv;
            cv.x = lo32(c0); cv.y = hi32(c0); cv.z = lo32(c1); cv.w = hi32(c1);
            rv.x = lo32(r0); rv.y = hi32(r0); rv.z = lo32(r1); rv.w = hi32(r1);
            #pragma unroll
            for (int m = 4; m <= 32; m <<= 1) {       // fold over 16 peers
                cv.x += __shfl_xor(cv.x, m, 64); rv.x += __shfl_xor(rv.x, m, 64);
                cv.y += __shfl_xor(cv.y, m, 64); rv.y += __shfl_xor(rv.y, m, 64);
                cv.z += __shfl_xor(cv.z, m, 64); rv.z += __shfl_xor(rv.z, m, 64);
                cv.w += __shfl_xor(cv.w, m, 64); rv.w += __shfl_xor(rv.w, m, 64);
            }
            if (lane < 4) {                           // lane == q here
                colqAll[4 * g + lane] = cv;           // colsums 16g+4q..+3
                rwave4[g][lane] = rv;                 // rowsums 16g+4q..+3
            }
        }
        if (g == 12) {   // grand total (identical fold order in every block)
            float vb = bsv[lane] + bsv[64 + lane] + bsv[128 + lane] + bsv[192 + lane];
            vb = wave_reduce_sum(vb);
            if (lane == 0) sG_s = vb;
        }
        __syncthreads();                              // B1: colq/rwave/sG ready

        const float sG  = sG_s;
        const float cc0 = INV_N + sG * (INV_N * INV_N);
        const f32x4 csub = colqAll[c] * INV_N;        // this thread's 4 cols
        const float* rw = (const float*)&rwave4[g][0];
        #pragma unroll
        for (int r = 0; r < 16; ++r) {
            const float a = cc0 - rw[r] * INV_N;
            x[r].x = fmaxf(x[r].x + a - csub.x, 0.f);
            x[r].y = fmaxf(x[r].y + a - csub.y, 0.f);
            x[r].z = fmaxf(x[r].z + a - csub.z, 0.f);
            x[r].w = fmaxf(x[r].w + a - csub.w, 0.f);
        }
        // next iter: part/rwave are wave-local; cq protected by B0; colqAll/
        // bsv/sG protected by B1/B0 barrier ordering (see header comment).
    }

    {   // final store (plain cached path)
        f32x4* xo = (f32x4*)Xout;
        const size_t base = (size_t)(bi * 256 + g * 16) * NV4 + (bj * 64 + c);
        #pragma unroll
        for (int r = 0; r < 16; ++r)
            xo[base + (size_t)r * NV4] = x[r];
    }
}

extern "C" void kernel_launch(void* const* d_in, const int* in_sizes, int n_in,
                              void* d_out, int out_size, void* d_ws, size_t ws_size,
                              hipStream_t stream)
{
    const float* X0 = (const float*)d_in[0];
    float* X = (float*)d_out;

    // ws: colF 512 KB | rowF 512 KB | pflag 32 KB   (~1.06 MB)
    u64* colF  = (u64*)d_ws;
    u64* rowF  = colF + 2 * NBLK * 128;
    u64* pflag = rowF + 2 * NBLK * 128;

    // Only flags need zeroing: data polls are exact-tag (tag in hi32 must
    // equal iter+1), so poisoned/stale words can never satisfy a poll.
    hipMemsetAsync((void*)pflag, 0, 2 * NBLK * 8 * sizeof(u64), stream);

    // 93.3 KB LDS -> 1 block/CU; grid == CU count -> all 256 blocks
    // co-resident (spin-waits are deadlock-free).
    persist11<<<dim3(NBLK), dim3(1024), 0, stream>>>(X0, X, colF, rowF, pflag);
}

// Round 4
// 242.363 us; speedup vs baseline: 1.1649x; 1.1649x over previous
//
#include <hip/hip_runtime.h>

// Frobenius — R13: R11 phase A verbatim + hoisted per-producer gathers +
// barrier-free tail.  (R11 = 166.6 us best; R12 = 199.8 us REGRESSION.)
//
// R12 post-mortem: moving wave0's colF fold+publish+vmcnt(0)-drain AFTER A1
// put a serial remote-store-ack (~1 us) on the flag edge of every iteration
// (+1.6 us/iter). Lesson: nothing serial on the flag edge — publishes must
// overlap other waves' work and drain collectively (R11's A1..A2 window).
//
// R13 keeps R11's phase A EXACTLY (A1; wave0 col fold+publish || all-wave
// row fold+publish; vmcnt(0); A2; t0 flag) and restructures phase B:
//  - FUSED poll: each wave polls its TWO producer flags (col peer g*16+bj,
//    row peer bi*16+g — wave-uniform addresses, coalesced to 2 loads/cycle);
//    threads t<256 additionally poll flag t for the blocksum payload.
//    As soon as a wave's two producers fire, it gathers its 1 KB (R11
//    addressing: 4 b64/thread, contiguous per wave) into LDS — BEFORE B0.
//    The global straggler path now costs flag-latency only, not flag+RTT.
//  - B1/B2 DELETED: after B0, folds are redundant in-register work —
//      sG:  every wave butterfly-reduces bsv (all lanes get the sum),
//      col: every thread folds cqB[0..15][c] (16 LDS v4 reads),
//      row: every wave butterfly-folds its own 16 rows from rqB,
//           broadcast via readlane-shfl.  Zero barriers after B0.
// Barriers/iter: A1, A2, B0 (was 5).
//
// LDS-reuse safety (no parity doubling): iter-k tail reads of cqB/rqB/bsv
// precede phase A(k+1) in program order; the gather/poll writes of k+1
// happen after A2(k+1), a full __syncthreads — every wave's k-tail is done.
// cqA (phase-A col partials) stays a SEPARATE buffer: its pre-A1(k+1)
// writes are not barrier-separated from post-B0(k) cqB reads, so no overlay.
//
// Global WAR (colF/rowF/pflag, parity-doubled): unchanged R11 transitive
// argument — B writes tag k+3 only after seeing all flags k+2, each set
// after that block passed B0(k), which required observing B's tag k+1.
// Early gathers don't weaken it: all reads still complete before the
// reader's next A2 vmcnt(0) drain -> before its next flag.

#define NN    4096
#define NV4   1024
#define NBLK  256
#define ITERS 20
#define INV_N (1.0f / 4096.0f)

typedef unsigned long long u64;
typedef float f32x4 __attribute__((ext_vector_type(4)));

__device__ __forceinline__ float wave_reduce_sum(float v) {
    #pragma unroll
    for (int m = 1; m < 64; m <<= 1) v += __shfl_xor(v, m, 64);
    return v;
}
__device__ __forceinline__ void st_b64(u64* p, u64 v) {
    __hip_atomic_store(p, v, __ATOMIC_RELAXED, __HIP_MEMORY_SCOPE_AGENT);
}
__device__ __forceinline__ u64 ld_b64(const u64* p) {
    return __hip_atomic_load(p, __ATOMIC_RELAXED, __HIP_MEMORY_SCOPE_AGENT);
}
__device__ __forceinline__ u64 packf2(float a, float b) {
    return (u64)__float_as_uint(a) | ((u64)__float_as_uint(b) << 32);
}
__device__ __forceinline__ float lo32(u64 u) { return __uint_as_float((unsigned)u); }
__device__ __forceinline__ float hi32(u64 u) { return __uint_as_float((unsigned)(u >> 32)); }

__global__ __launch_bounds__(1024, 4)
void persist12(const float* __restrict__ X0, float* __restrict__ Xout,
               u64* __restrict__ colF,    // [2][256][128] b64 = 2 packed f32
               u64* __restrict__ rowF,    // [2][256][128]
               u64* __restrict__ pflag)   // [2][256] stride-8 u64 (64 B apart)
{
    const int t    = threadIdx.x;
    const int lane = t & 63;
    const int g    = t >> 6;          // wave = 16-row group
    const int c    = lane;            // 4-col quad
    const int b    = blockIdx.x;
    const int bi   = b >> 4;
    const int bj   = b & 15;

    // 117 KB total -> 1 block/CU (grid == 256 == #CUs).
    __shared__ float part[16][64][17];   // row-partial transpose (69.6 KB)
    __shared__ f32x4 cqA[16][64];        // phase-A col partials (16 KB)
    __shared__ f32x4 cqB[16][64];        // gathered col partials (16 KB)
    __shared__ f32x4 rqB[16][64];        // gathered row partials (16 KB)
    __shared__ float bsv[256];           // peer blocksums (1 KB)

    f32x4 x[16];
    {
        const f32x4* xi = (const f32x4*)X0;
        const size_t base = (size_t)(bi * 256 + g * 16) * NV4 + (bj * 64 + c);
        #pragma unroll
        for (int r = 0; r < 16; ++r)
            x[r] = xi[base + (size_t)r * NV4];
    }

    for (int iter = 0; iter < ITERS; ++iter) {
        const int p = iter & 1;
        const u64 tagv = (u64)(iter + 1);

        // ---- phase A (R11 verbatim): partials, publish, drain, flag
        f32x4 cacc = x[0];
        #pragma unroll
        for (int r = 1; r < 16; ++r) cacc += x[r];
        cqA[g][c] = cacc;                             // per-wave col partial
        #pragma unroll
        for (int r = 0; r < 16; ++r)                  // bank-safe (17 pad)
            part[g][c][r] = (x[r].x + x[r].y) + (x[r].z + x[r].w);
        __syncthreads();                              // A1

        float bs = 0.f;
        if (g == 0) {   // fold 16 waves' col partials, publish 256 cols
            f32x4 vq = cqA[0][c];
            #pragma unroll
            for (int k = 1; k < 16; ++k) vq += cqA[k][c];
            u64* dst = colF + (((size_t)(p * NBLK + b)) << 7) + 2 * c;
            st_b64(dst,     packf2(vq.x, vq.y));
            st_b64(dst + 1, packf2(vq.z, vq.w));
            bs = wave_reduce_sum((vq.x + vq.y) + (vq.z + vq.w));
        }
        {   // row fold: wave g's 16 rows over 64 col-quads (LDS transpose)
            const int r_ = lane & 15, q_ = lane >> 4;
            float v = 0.f;
            #pragma unroll
            for (int k = 0; k < 16; ++k) v += part[g][q_ * 16 + k][r_];
            v += __shfl_xor(v, 16, 64);
            v += __shfl_xor(v, 32, 64);
            float vp = __shfl_xor(v, 1, 64);          // partner row value
            if (lane < 16 && (lane & 1) == 0)         // 8 b64 per wave
                st_b64(rowF + (((size_t)(p * NBLK + b)) << 7) + 8 * g + (lane >> 1),
                       packf2(v, vp));
        }
        asm volatile("s_waitcnt vmcnt(0)" ::: "memory");  // all stores acked
        __syncthreads();                                  // A2: block drained
        if (t == 0)
            st_b64(pflag + ((size_t)(p * NBLK + b) << 3),
                   (tagv << 32) | (u64)__float_as_uint(bs));

        // ---- phase B: fused poll + hoisted gather (pre-B0)
        const int fcsrc = g * 16 + bj;    // col producer (wave-uniform)
        const int frsrc = bi * 16 + g;    // row producer (wave-uniform)
        {
            const u64* fc = pflag + ((size_t)(p * NBLK + fcsrc) << 3);
            const u64* fr = pflag + ((size_t)(p * NBLK + frsrc) << 3);
            const u64* fb = pflag + ((size_t)(p * NBLK + (t & 255)) << 3);
            bool dc = false, dr = false, db = (t >= 256);
            u64 ub = 0;
            // loop 1: wait for this wave's two producers (bsv opportunistic)
            while (!(dc && dr)) {
                if (!dc && (ld_b64(fc) >> 32) == tagv) dc = true;
                if (!dr && (ld_b64(fr) >> 32) == tagv) dr = true;
                if (!db) { u64 u = ld_b64(fb);
                           if ((u >> 32) == tagv) { ub = u; db = true; } }
                if (!(dc && dr)) __builtin_amdgcn_s_sleep(1);
            }
            asm volatile("" ::: "memory");
            {   // gather 1 KB/wave (R11 addressing), park in LDS
                const u64* cp = colF + (((size_t)(p * NBLK + fcsrc)) << 7) + 2 * c;
                const u64* rp = rowF + (((size_t)(p * NBLK + frsrc)) << 7) + 2 * c;
                u64 c0 = ld_b64(cp), c1 = ld_b64(cp + 1);
                u64 r0 = ld_b64(rp), r1 = ld_b64(rp + 1);
                f32x4 cv, rv;
                cv.x = lo32(c0); cv.y = hi32(c0); cv.z = lo32(c1); cv.w = hi32(c1);
                rv.x = lo32(r0); rv.y = hi32(r0); rv.z = lo32(r1); rv.w = hi32(r1);
                cqB[g][c] = cv;
                rqB[g][c] = rv;
            }
            // loop 2: finish the bsv poll (t<256 lanes only)
            while (!db) {
                u64 u = ld_b64(fb);
                if ((u >> 32) == tagv) { ub = u; db = true; }
                else __builtin_amdgcn_s_sleep(1);
            }
            if (t < 256) bsv[t] = lo32(ub);
        }
        asm volatile("" ::: "memory");
        __syncthreads();    // B0: all gathers in LDS, bsv complete

        // ---- barrier-free tail: redundant per-wave/per-thread folds
        // sG: every wave reduces bsv (butterfly -> sum in ALL lanes)
        float vb = bsv[lane] + bsv[64 + lane] + bsv[128 + lane] + bsv[192 + lane];
        const float sG = wave_reduce_sum(vb);
        // col sums for this thread's 4 columns: fold 16 peer partials
        f32x4 cs = cqB[0][c];
        #pragma unroll
        for (int k = 1; k < 16; ++k) cs += cqB[k][c];
        // row sums for this wave's 16 rows: butterfly over 16 peers
        float vr;
        {
            const int rr = lane & 15, kk = lane >> 4;
            const float* rqf = (const float*)&rqB[0][0];
            vr = 0.f;
            #pragma unroll
            for (int j = 0; j < 4; ++j)
                vr += rqf[(((4 * kk + j) * 64) + (4 * g + (rr >> 2))) * 4 + (rr & 3)];
            vr += __shfl_xor(vr, 16, 64);
            vr += __shfl_xor(vr, 32, 64);   // lane class rr holds rowsum[16g+rr]
        }

        const float cc0 = INV_N + sG * (INV_N * INV_N);
        const f32x4 csub = cs * INV_N;
        #pragma unroll
        for (int r = 0; r < 16; ++r) {
            const float rwr = __shfl(vr, r, 64);      // rowsum[16g+r]
            const float a = cc0 - rwr * INV_N;
            x[r].x = fmaxf(x[r].x + a - csub.x, 0.f);
            x[r].y = fmaxf(x[r].y + a - csub.y, 0.f);
            x[r].z = fmaxf(x[r].z + a - csub.z, 0.f);
            x[r].w = fmaxf(x[r].w + a - csub.w, 0.f);
        }
        // iter-k tail reads precede A-phase(k+1) in program order; k+1's
        // LDS writes to cqB/rqB/bsv happen after A2(k+1) -> race-free.
    }

    {   // final store (plain cached path)
        f32x4* xo = (f32x4*)Xout;
        const size_t base = (size_t)(bi * 256 + g * 16) * NV4 + (bj * 64 + c);
        #pragma unroll
        for (int r = 0; r < 16; ++r)
            xo[base + (size_t)r * NV4] = x[r];
    }
}

extern "C" void kernel_launch(void* const* d_in, const int* in_sizes, int n_in,
                              void* d_out, int out_size, void* d_ws, size_t ws_size,
                              hipStream_t stream)
{
    const float* X0 = (const float*)d_in[0];
    float* X = (float*)d_out;

    // ws: colF 512 KB | rowF 512 KB | pflag 32 KB   (~1.06 MB)
    u64* colF  = (u64*)d_ws;
    u64* rowF  = colF + 2 * NBLK * 128;
    u64* pflag = rowF + 2 * NBLK * 128;

    // Only flags need zeroing: data polls are exact-tag (tag in hi32 must
    // equal iter+1), so poisoned/stale words can never satisfy a poll.
    hipMemsetAsync((void*)pflag, 0, 2 * NBLK * 8 * sizeof(u64), stream);

    // 117 KB LDS -> 1 block/CU; grid == CU count -> all 256 blocks
    // co-resident (spin-waits are deadlock-free).
    persist12<<<dim3(NBLK), dim3(1024), 0, stream>>>(X0, X, colF, rowF, pflag);
}